// Round 1
// baseline (2057.784 us; speedup 1.0000x reference)
//
#include <hip/hip_runtime.h>

// ---------------------------------------------------------------------------
// GraphSAGE 3-layer + MLP head, fp32. N=100000, E=3200000.
// Round 1: correctness-first. Scatter-add with atomics, fused linear layers.
// ---------------------------------------------------------------------------

__global__ void degree_kernel(const int* __restrict__ dst, float* __restrict__ cnt, int E) {
    int e = blockIdx.x * blockDim.x + threadIdx.x;
    if (e < E) atomicAdd(&cnt[dst[e]], 1.0f);
}

// one thread per (edge, feature); F is a power of two so div/mod are shifts
template <int F>
__global__ void scatter_kernel(const int* __restrict__ src, const int* __restrict__ dst,
                               const float* __restrict__ h, float* __restrict__ agg,
                               long long total) {
    long long tid = (long long)blockIdx.x * blockDim.x + threadIdx.x;
    if (tid >= total) return;
    int e = (int)(tid / F);
    int f = (int)(tid & (F - 1));
    int s = src[e];
    int d = dst[e];
    atomicAdd(&agg[(long long)d * F + f], h[(long long)s * F + f]);
}

// out[n][j] = relu( (agg[n]/max(cnt,1)) @ Wl + b + x[n] @ Wr )
// blockDim.x must be a multiple of FOUT; each thread owns one (node, j).
template <int FIN, int FOUT>
__global__ void sage_layer_kernel(const float* __restrict__ agg, const float* __restrict__ cnt,
                                  const float* __restrict__ x,
                                  const float* __restrict__ Wl, const float* __restrict__ b,
                                  const float* __restrict__ Wr,
                                  float* __restrict__ out, int n) {
    __shared__ float sWl[FIN * FOUT];
    __shared__ float sWr[FIN * FOUT];
    __shared__ float sb[FOUT];
    for (int i = threadIdx.x; i < FIN * FOUT; i += blockDim.x) {
        sWl[i] = Wl[i];
        sWr[i] = Wr[i];
    }
    for (int i = threadIdx.x; i < FOUT; i += blockDim.x) sb[i] = b[i];
    __syncthreads();

    const int nodes_per_block = blockDim.x / FOUT;
    const int local = threadIdx.x / FOUT;
    const int j = threadIdx.x % FOUT;
    const int node = blockIdx.x * nodes_per_block + local;
    if (node >= n) return;

    const float inv = 1.0f / fmaxf(cnt[node], 1.0f);
    const float* arow = agg + (long long)node * FIN;
    const float* xrow = x + (long long)node * FIN;
    float acc = sb[j];
#pragma unroll
    for (int k = 0; k < FIN; k++) {
        acc += (arow[k] * inv) * sWl[k * FOUT + j] + xrow[k] * sWr[k * FOUT + j];
    }
    out[(long long)node * FOUT + j] = fmaxf(acc, 0.0f);
}

// out[n] = relu(h3[n] @ W4 + b4) @ W5 + b5   (32 -> 16 -> 1)
__global__ void head_kernel(const float* __restrict__ h3, const float* __restrict__ W4,
                            const float* __restrict__ b4, const float* __restrict__ W5,
                            const float* __restrict__ b5, float* __restrict__ out, int n) {
    __shared__ float sW4[32 * 16];
    __shared__ float sb4[16];
    __shared__ float sW5[16];
    for (int i = threadIdx.x; i < 32 * 16; i += blockDim.x) sW4[i] = W4[i];
    if (threadIdx.x < 16) {
        sb4[threadIdx.x] = b4[threadIdx.x];
        sW5[threadIdx.x] = W5[threadIdx.x];
    }
    __syncthreads();

    int node = blockIdx.x * blockDim.x + threadIdx.x;
    if (node >= n) return;

    float hl[32];
#pragma unroll
    for (int k = 0; k < 32; k++) hl[k] = h3[(long long)node * 32 + k];

    float acc = b5[0];
#pragma unroll
    for (int j = 0; j < 16; j++) {
        float t = sb4[j];
#pragma unroll
        for (int k = 0; k < 32; k++) t += hl[k] * sW4[k * 16 + j];
        acc += fmaxf(t, 0.0f) * sW5[j];
    }
    out[node] = acc;
}

extern "C" void kernel_launch(void* const* d_in, const int* in_sizes, int n_in,
                              void* d_out, int out_size, void* d_ws, size_t ws_size,
                              hipStream_t stream) {
    const float* x   = (const float*)d_in[0];
    const int*   ei  = (const int*)d_in[1];   // int32 per harness contract
    const float* W1l = (const float*)d_in[2];
    const float* b1  = (const float*)d_in[3];
    const float* W1r = (const float*)d_in[4];
    const float* W2l = (const float*)d_in[5];
    const float* b2  = (const float*)d_in[6];
    const float* W2r = (const float*)d_in[7];
    const float* W3l = (const float*)d_in[8];
    const float* b3  = (const float*)d_in[9];
    const float* W3r = (const float*)d_in[10];
    const float* W4  = (const float*)d_in[11];
    const float* b4  = (const float*)d_in[12];
    const float* W5  = (const float*)d_in[13];
    const float* b5  = (const float*)d_in[14];
    float* out = (float*)d_out;

    const int n = in_sizes[0] / 4;
    const int E = in_sizes[1] / 2;
    const int* src = ei;
    const int* dst = ei + E;

    // workspace layout (all 256B-aligned)
    char* ws = (char*)d_ws;
    size_t off = 0;
    auto alloc = [&](size_t bytes) {
        char* p = ws + off;
        off += (bytes + 255) & ~(size_t)255;
        return p;
    };
    float* cnt = (float*)alloc((size_t)n * sizeof(float));
    float* agg = (float*)alloc((size_t)n * 64 * sizeof(float));
    float* hA  = (float*)alloc((size_t)n * 64 * sizeof(float));
    float* hB  = (float*)alloc((size_t)n * 64 * sizeof(float));
    (void)ws_size;

    const int BT = 256;

    // degree (shared across layers)
    hipMemsetAsync(cnt, 0, (size_t)n * sizeof(float), stream);
    degree_kernel<<<(E + BT - 1) / BT, BT, 0, stream>>>(dst, cnt, E);

    // ---- layer 1: x[N,4] -> hA[N,64] ----
    hipMemsetAsync(agg, 0, (size_t)n * 4 * sizeof(float), stream);
    {
        long long total = (long long)E * 4;
        scatter_kernel<4><<<(int)((total + BT - 1) / BT), BT, 0, stream>>>(src, dst, x, agg, total);
    }
    sage_layer_kernel<4, 64><<<(n + 3) / 4, 256, 0, stream>>>(agg, cnt, x, W1l, b1, W1r, hA, n);

    // ---- layer 2: hA[N,64] -> hB[N,64] ----
    hipMemsetAsync(agg, 0, (size_t)n * 64 * sizeof(float), stream);
    {
        long long total = (long long)E * 64;
        scatter_kernel<64><<<(int)((total + BT - 1) / BT), BT, 0, stream>>>(src, dst, hA, agg, total);
    }
    sage_layer_kernel<64, 64><<<(n + 3) / 4, 256, 0, stream>>>(agg, cnt, hA, W2l, b2, W2r, hB, n);

    // ---- layer 3: hB[N,64] -> hA[N,32] (hA's h1 contents are dead) ----
    hipMemsetAsync(agg, 0, (size_t)n * 64 * sizeof(float), stream);
    {
        long long total = (long long)E * 64;
        scatter_kernel<64><<<(int)((total + BT - 1) / BT), BT, 0, stream>>>(src, dst, hB, agg, total);
    }
    sage_layer_kernel<64, 32><<<(n + 7) / 8, 256, 0, stream>>>(agg, cnt, hB, W3l, b3, W3r, hA, n);

    // ---- head: hA[N,32] -> out[N] ----
    head_kernel<<<(n + BT - 1) / BT, BT, 0, stream>>>(hA, W4, b4, W5, b5, out, n);
}

// Round 2
// 967.350 us; speedup vs baseline: 2.1272x; 2.1272x over previous
//
#include <hip/hip_runtime.h>

// ---------------------------------------------------------------------------
// GraphSAGE 3-layer + MLP head, fp32. N=100000, E=3200000.
// Round 2: CSR pull-based aggregation (no feature atomics).
//   - on-device CSR build each call: hist -> 2-level scan -> cursor fill
//   - pull64: one wave per node, lane=feature, coalesced 256B row gathers
//   - sage layer stages rows in LDS => layer-2 output can alias agg in-place
//   - h3 (N*32 floats = 12.8MB) reuses the dead col buffer (E ints = 12.8MB)
// ---------------------------------------------------------------------------

__global__ void hist_kernel(const int* __restrict__ dst, int* __restrict__ deg, int E) {
    int e = blockIdx.x * blockDim.x + threadIdx.x;
    if (e < E) atomicAdd(&deg[dst[e]], 1);
}

// Level A: 1024 elements per block (4/thread); writes per-element exclusive
// prefix (within block) and the block total.
__global__ void scan_blocks_kernel(const int* __restrict__ deg, int* __restrict__ rowptr,
                                   int* __restrict__ blocksum, int n) {
    __shared__ int s[256];
    int base = blockIdx.x * 1024;
    int t = threadIdx.x;
    int v[4];
    int loc = 0;
#pragma unroll
    for (int k = 0; k < 4; k++) {
        int i = base + t * 4 + k;
        v[k] = (i < n) ? deg[i] : 0;
        loc += v[k];
    }
    s[t] = loc;
    __syncthreads();
    for (int off = 1; off < 256; off <<= 1) {
        int xv = (t >= off) ? s[t - off] : 0;
        __syncthreads();
        s[t] += xv;
        __syncthreads();
    }
    if (t == 255) blocksum[blockIdx.x] = s[255];
    int run = s[t] - loc;  // exclusive prefix of this thread's chunk
#pragma unroll
    for (int k = 0; k < 4; k++) {
        int i = base + t * 4 + k;
        if (i < n) rowptr[i] = run;
        run += v[k];
    }
}

// Level B: single block exclusive scan of block sums (nb <= 128)
__global__ void scan_sums_kernel(int* __restrict__ blocksum, int nb) {
    __shared__ int s[128];
    int t = threadIdx.x;
    int v = (t < nb) ? blocksum[t] : 0;
    s[t] = v;
    __syncthreads();
    for (int off = 1; off < 128; off <<= 1) {
        int xv = (t >= off) ? s[t - off] : 0;
        __syncthreads();
        s[t] += xv;
        __syncthreads();
    }
    if (t < nb) blocksum[t] = s[t] - v;
}

// Level C: add block offsets
__global__ void scan_add_kernel(int* __restrict__ rowptr, const int* __restrict__ blocksum, int n) {
    int i = blockIdx.x * blockDim.x + threadIdx.x;
    if (i < n) rowptr[i] += blocksum[i >> 10];
}

// cursor-scatter edges into CSR col array
__global__ void fill_kernel(const int* __restrict__ src, const int* __restrict__ dst,
                            int* __restrict__ pos, int* __restrict__ col, int E) {
    int e = blockIdx.x * blockDim.x + threadIdx.x;
    if (e < E) {
        int p = atomicAdd(&pos[dst[e]], 1);
        col[p] = src[e];
    }
}

// layer-1 aggregation: thread per node, float4 gather of x
__global__ void pull4_kernel(const int* __restrict__ rowptr, const int* __restrict__ deg,
                             const int* __restrict__ col, const float4* __restrict__ x,
                             float4* __restrict__ agg, int n) {
    int node = blockIdx.x * blockDim.x + threadIdx.x;
    if (node >= n) return;
    int beg = rowptr[node];
    int end = beg + deg[node];
    float4 a = {0.f, 0.f, 0.f, 0.f};
    for (int i = beg; i < end; i++) {
        float4 v = x[col[i]];
        a.x += v.x; a.y += v.y; a.z += v.z; a.w += v.w;
    }
    agg[node] = a;
}

// F=64 aggregation: one wave per node, lane = feature. Coalesced 256B row
// reads per neighbor; unroll 4 neighbors for ILP. No atomics.
__global__ void pull64_kernel(const int* __restrict__ rowptr, const int* __restrict__ deg,
                              const int* __restrict__ col, const float* __restrict__ h,
                              float* __restrict__ agg, int n) {
    int wave = threadIdx.x >> 6;
    int lane = threadIdx.x & 63;
    int node = blockIdx.x * 4 + wave;
    if (node >= n) return;
    int beg = rowptr[node];
    int end = beg + deg[node];
    float acc = 0.f;
    int i = beg;
    for (; i + 4 <= end; i += 4) {
        int c0 = col[i], c1 = col[i + 1], c2 = col[i + 2], c3 = col[i + 3];
        float a0 = h[(size_t)c0 * 64 + lane];
        float a1 = h[(size_t)c1 * 64 + lane];
        float a2 = h[(size_t)c2 * 64 + lane];
        float a3 = h[(size_t)c3 * 64 + lane];
        acc += a0 + a1 + a2 + a3;
    }
    for (; i < end; i++) acc += h[(size_t)col[i] * 64 + lane];
    agg[(size_t)node * 64 + lane] = acc;
}

// out[n][j] = relu( (agg[n]/max(deg,1)) @ Wl + b + x[n] @ Wr )
// Rows staged in LDS before any write => `out` may alias `agg` (same stride).
template <int FIN, int FOUT>
__global__ void sage_layer_kernel(const float* __restrict__ agg, const int* __restrict__ deg,
                                  const float* __restrict__ x,
                                  const float* __restrict__ Wl, const float* __restrict__ b,
                                  const float* __restrict__ Wr,
                                  float* __restrict__ out, int n) {
    constexpr int NPB = 256 / FOUT;  // nodes per block
    __shared__ float sWl[FIN * FOUT];
    __shared__ float sWr[FIN * FOUT];
    __shared__ float sb[FOUT];
    __shared__ float sA[NPB][FIN];
    __shared__ float sX[NPB][FIN];
    for (int i = threadIdx.x; i < FIN * FOUT; i += 256) {
        sWl[i] = Wl[i];
        sWr[i] = Wr[i];
    }
    if (threadIdx.x < FOUT) sb[threadIdx.x] = b[threadIdx.x];
    const int first = blockIdx.x * NPB;
    for (int i = threadIdx.x; i < NPB * FIN; i += 256) {
        int local = i / FIN, k = i % FIN;
        int node = first + local;
        float av = 0.f, xv = 0.f;
        if (node < n) {
            av = agg[(size_t)node * FIN + k];
            xv = x[(size_t)node * FIN + k];
        }
        sA[local][k] = av;
        sX[local][k] = xv;
    }
    __syncthreads();

    const int local = threadIdx.x / FOUT;
    const int j = threadIdx.x % FOUT;
    const int node = first + local;
    if (node >= n) return;
    const float inv = 1.0f / (float)max(deg[node], 1);
    float accA = 0.f, accX = 0.f;
#pragma unroll
    for (int k = 0; k < FIN; k++) {
        accA += sA[local][k] * sWl[k * FOUT + j];
        accX += sX[local][k] * sWr[k * FOUT + j];
    }
    float acc = sb[j] + inv * accA + accX;
    out[(size_t)node * FOUT + j] = fmaxf(acc, 0.0f);
}

// out[n] = relu(h3[n] @ W4 + b4) @ W5 + b5   (32 -> 16 -> 1)
__global__ void head_kernel(const float* __restrict__ h3, const float* __restrict__ W4,
                            const float* __restrict__ b4, const float* __restrict__ W5,
                            const float* __restrict__ b5, float* __restrict__ out, int n) {
    __shared__ float sW4[32 * 16];
    __shared__ float sb4[16];
    __shared__ float sW5[16];
    for (int i = threadIdx.x; i < 32 * 16; i += blockDim.x) sW4[i] = W4[i];
    if (threadIdx.x < 16) {
        sb4[threadIdx.x] = b4[threadIdx.x];
        sW5[threadIdx.x] = W5[threadIdx.x];
    }
    __syncthreads();

    int node = blockIdx.x * blockDim.x + threadIdx.x;
    if (node >= n) return;

    float hl[32];
#pragma unroll
    for (int k = 0; k < 32; k++) hl[k] = h3[(size_t)node * 32 + k];

    float acc = b5[0];
#pragma unroll
    for (int j = 0; j < 16; j++) {
        float t = sb4[j];
#pragma unroll
        for (int k = 0; k < 32; k++) t += hl[k] * sW4[k * 16 + j];
        acc += fmaxf(t, 0.0f) * sW5[j];
    }
    out[node] = acc;
}

extern "C" void kernel_launch(void* const* d_in, const int* in_sizes, int n_in,
                              void* d_out, int out_size, void* d_ws, size_t ws_size,
                              hipStream_t stream) {
    const float* x   = (const float*)d_in[0];
    const int*   ei  = (const int*)d_in[1];
    const float* W1l = (const float*)d_in[2];
    const float* b1  = (const float*)d_in[3];
    const float* W1r = (const float*)d_in[4];
    const float* W2l = (const float*)d_in[5];
    const float* b2  = (const float*)d_in[6];
    const float* W2r = (const float*)d_in[7];
    const float* W3l = (const float*)d_in[8];
    const float* b3  = (const float*)d_in[9];
    const float* W3r = (const float*)d_in[10];
    const float* W4  = (const float*)d_in[11];
    const float* b4  = (const float*)d_in[12];
    const float* W5  = (const float*)d_in[13];
    const float* b5  = (const float*)d_in[14];
    float* out = (float*)d_out;

    const int n = in_sizes[0] / 4;
    const int E = in_sizes[1] / 2;
    const int* src = ei;
    const int* dst = ei + E;

    char* ws = (char*)d_ws;
    size_t off = 0;
    auto alloc = [&](size_t bytes) {
        char* p = ws + off;
        off += (bytes + 255) & ~(size_t)255;
        return p;
    };
    int*   deg      = (int*)alloc((size_t)n * sizeof(int));
    int*   rowptr   = (int*)alloc((size_t)n * sizeof(int));
    int*   pos      = (int*)alloc((size_t)n * sizeof(int));
    int*   blocksum = (int*)alloc(128 * sizeof(int));
    int*   col      = (int*)alloc((size_t)E * sizeof(int));       // 12.8 MB; reused for h3
    float* agg4     = (float*)alloc((size_t)n * 4 * sizeof(float));
    float* agg      = (float*)alloc((size_t)n * 64 * sizeof(float));
    float* hA       = (float*)alloc((size_t)n * 64 * sizeof(float));
    (void)ws_size;

    const int BT = 256;
    const int nb = (n + 1023) / 1024;  // 98 for n=100000 (<=128 required)

    // ---- CSR build ----
    hipMemsetAsync(deg, 0, (size_t)n * sizeof(int), stream);
    hist_kernel<<<(E + BT - 1) / BT, BT, 0, stream>>>(dst, deg, E);
    scan_blocks_kernel<<<nb, 256, 0, stream>>>(deg, rowptr, blocksum, n);
    scan_sums_kernel<<<1, 128, 0, stream>>>(blocksum, nb);
    scan_add_kernel<<<(n + BT - 1) / BT, BT, 0, stream>>>(rowptr, blocksum, n);
    hipMemcpyAsync(pos, rowptr, (size_t)n * sizeof(int), hipMemcpyDeviceToDevice, stream);
    fill_kernel<<<(E + BT - 1) / BT, BT, 0, stream>>>(src, dst, pos, col, E);

    // ---- layer 1: x[N,4] -> hA[N,64] ----
    pull4_kernel<<<(n + BT - 1) / BT, BT, 0, stream>>>(rowptr, deg, col, (const float4*)x,
                                                       (float4*)agg4, n);
    sage_layer_kernel<4, 64><<<(n + 3) / 4, 256, 0, stream>>>(agg4, deg, x, W1l, b1, W1r, hA, n);

    // ---- layer 2: hA[N,64] -> h2 (in-place into agg) ----
    pull64_kernel<<<(n + 3) / 4, 256, 0, stream>>>(rowptr, deg, col, hA, agg, n);
    sage_layer_kernel<64, 64><<<(n + 3) / 4, 256, 0, stream>>>(agg, deg, hA, W2l, b2, W2r, agg, n);

    // ---- layer 3: h2=agg -> h3 (into col buffer; col is dead after pull) ----
    pull64_kernel<<<(n + 3) / 4, 256, 0, stream>>>(rowptr, deg, col, agg, hA, n);
    float* h3 = (float*)col;  // N*32 floats == E ints == 12.8 MB
    sage_layer_kernel<64, 32><<<(n + 7) / 8, 256, 0, stream>>>(hA, deg, agg, W3l, b3, W3r, h3, n);

    // ---- head: h3[N,32] -> out[N] ----
    head_kernel<<<(n + BT - 1) / BT, BT, 0, stream>>>(h3, W4, b4, W5, b5, out, n);
}